// Round 2
// baseline (207.424 us; speedup 1.0000x reference)
//
#include <hip/hip_runtime.h>

// Depthwise causal conv1d, k=3.
// x: (8, 768, 4096) fp32, weight: (768, 1, 3) fp32, y: (8, 768, 4096) fp32.
// y[n,c,t] = w[c,0]*x[t-2] + w[c,1]*x[t-1] + w[c,2]*x[t], zeros left of t=0.
//
// Memory-bound: ~201 MB total traffic -> floor ~30 us at measured 6.8 TB/s.
// v3 == v2 with the launch fixed: out_size is an ELEMENT count (v1 passed
// with rows = out_size / CONV_L); v2's /sizeof(float) launched 1/4 of rows.
// Kernel body: 4 float4 (64 B) per thread, one block per row. 4 independent
// dwordx4 loads per thread give MLP; per-wave setup (kernarg/weight s_loads,
// shfl, history branch) amortizes over 4x the bytes. Nontemporal both sides.

#define CONV_L 4096
#define CONV_C 768

typedef float vfloat4 __attribute__((ext_vector_type(4)));

__global__ __launch_bounds__(256) void dwconv1d_k3_x4(
    const float* __restrict__ x,
    const float* __restrict__ w,
    float* __restrict__ y)
{
    const int row = blockIdx.x;          // 0..6143, block-uniform
    const int c   = row % CONV_C;        // uniform -> weight loads are scalar

    const float w0 = w[c * 3 + 0];
    const float w1 = w[c * 3 + 1];
    const float w2 = w[c * 3 + 2];

    const float* xrow = x + (size_t)row * CONV_L;
    float*       yrow = y + (size_t)row * CONV_L;

    const int t = threadIdx.x;           // thread covers floats [16t, 16t+16)
    const vfloat4* xin = (const vfloat4*)xrow + (t << 2);

    // 4 independent 16B loads -> 4 outstanding VMEM ops per lane.
    vfloat4 c0 = __builtin_nontemporal_load(xin + 0);
    vfloat4 c1 = __builtin_nontemporal_load(xin + 1);
    vfloat4 c2 = __builtin_nontemporal_load(xin + 2);
    vfloat4 c3 = __builtin_nontemporal_load(xin + 3);

    // History for the first float4 comes from the previous lane's last float4.
    float xm1 = __shfl_up(c3.w, 1);      // x[16t-1]
    float xm2 = __shfl_up(c3.z, 1);      // x[16t-2]
    if ((t & 63) == 0) {
        if (t == 0) {
            xm1 = 0.0f; xm2 = 0.0f;      // causal left edge of the row
        } else {
            // (16t-2)*4 bytes is 8B-aligned -> single dwordx2.
            const float2 h = *(const float2*)(xrow + (t << 4) - 2);
            xm2 = h.x; xm1 = h.y;
        }
    }

    vfloat4 o0, o1, o2, o3;
    o0.x = w0 * xm2  + w1 * xm1  + w2 * c0.x;
    o0.y = w0 * xm1  + w1 * c0.x + w2 * c0.y;
    o0.z = w0 * c0.x + w1 * c0.y + w2 * c0.z;
    o0.w = w0 * c0.y + w1 * c0.z + w2 * c0.w;

    o1.x = w0 * c0.z + w1 * c0.w + w2 * c1.x;
    o1.y = w0 * c0.w + w1 * c1.x + w2 * c1.y;
    o1.z = w0 * c1.x + w1 * c1.y + w2 * c1.z;
    o1.w = w0 * c1.y + w1 * c1.z + w2 * c1.w;

    o2.x = w0 * c1.z + w1 * c1.w + w2 * c2.x;
    o2.y = w0 * c1.w + w1 * c2.x + w2 * c2.y;
    o2.z = w0 * c2.x + w1 * c2.y + w2 * c2.z;
    o2.w = w0 * c2.y + w1 * c2.z + w2 * c2.w;

    o3.x = w0 * c2.z + w1 * c2.w + w2 * c3.x;
    o3.y = w0 * c2.w + w1 * c3.x + w2 * c3.y;
    o3.z = w0 * c3.x + w1 * c3.y + w2 * c3.z;
    o3.w = w0 * c3.y + w1 * c3.z + w2 * c3.w;

    vfloat4* yout = (vfloat4*)yrow + (t << 2);
    __builtin_nontemporal_store(o0, yout + 0);
    __builtin_nontemporal_store(o1, yout + 1);
    __builtin_nontemporal_store(o2, yout + 2);
    __builtin_nontemporal_store(o3, yout + 3);
}

extern "C" void kernel_launch(void* const* d_in, const int* in_sizes, int n_in,
                              void* d_out, int out_size, void* d_ws, size_t ws_size,
                              hipStream_t stream)
{
    const float* x = (const float*)d_in[0];
    const float* w = (const float*)d_in[1];
    float* y = (float*)d_out;

    const int rows = out_size / CONV_L;   // out_size is ELEMENTS: 8*768 = 6144
    dwconv1d_k3_x4<<<rows, 256, 0, stream>>>(x, w, y);
}